// Round 2
// baseline (1576.662 us; speedup 1.0000x reference)
//
#include <hip/hip_runtime.h>

typedef unsigned short u16;
typedef unsigned int u32;
typedef __attribute__((ext_vector_type(8))) __bf16 bf16x8;
typedef __attribute__((ext_vector_type(4))) float f32x4;

#define D_ 1024
#define H_ 4096
#define E_ 8
#define NT_ 4096          // B*T tokens
#define RCAP_ 8448        // 8192 rows + per-expert pad-to-8 + 128 tile over-read slack

// Packed operand layout (all GEMM inputs): P[k>>6][row][64] bf16, with XOR swizzle
// baked per row: element (k&63) stored at ((((k&63)>>3) ^ (row&7))<<3) | (k&7).
// -> global_load_lds staging of a 128-row x 64-k tile is 16KB fully contiguous;
// -> ds_read_b128 with the same XOR is bank-conflict-free (rule #21 pattern).

// ---------- helpers ----------
__device__ __forceinline__ u16 f2b(float f) {   // fp32 -> bf16 bits, RNE
  u32 u = __float_as_uint(f);
  u += 0x7fffu + ((u >> 16) & 1u);
  return (u16)(u >> 16);
}

__device__ __forceinline__ void glds16(const u16* g, u16* l) {
  // async global->LDS, 16B per lane; LDS dest = wave-uniform base + lane*16
  __builtin_amdgcn_global_load_lds((const __attribute__((address_space(1))) void*)g,
                                   (__attribute__((address_space(3))) void*)l, 16, 0, 0);
}

// ---------- small kernels ----------
__global__ void init_ints(int* p, int n) {
  int i = threadIdx.x;
  if (i < n) p[i] = 0;
}

// x [NT][D] f32 -> xp packed [D/64][NT][64] bf16 (swizzled by token&7)
__global__ void pack_x(const float* __restrict__ x, u16* __restrict__ xp) {
  const int t = blockIdx.x, i = threadIdx.x;          // 256 threads, 4 f32 each
  float4 v = ((const float4*)(x + (size_t)t * D_))[i];
  const int kb = i >> 4, ch = (i >> 1) & 7, sub = (i & 1) * 4;
  u16 tmp[4] = {f2b(v.x), f2b(v.y), f2b(v.z), f2b(v.w)};
  *(uint2*)(xp + ((size_t)kb * NT_ + t) * 64 + ((ch ^ (t & 7)) << 3) + sub) = *(uint2*)tmp;
}

// src [Z][Kdim][Rdim] f32 (+optional src2 for gu-interleave) -> dst [Z][Kdim/64][Rout][64] bf16
// interleave: dst rows 32q+s: s<16 -> src row 16q+s ; s>=16 -> src2 row 16q+(s-16)
__global__ void pack_b(const float* __restrict__ src, const float* __restrict__ src2,
                       u16* __restrict__ dst, int Kdim, int Rdim) {
  const int r0 = blockIdx.x * 64, k0 = blockIdx.y * 64, z = blockIdx.z;
  const int Rout = src2 ? (Rdim * 2) : Rdim;
  src += (size_t)z * Kdim * Rdim;
  if (src2) src2 += (size_t)z * Kdim * Rdim;
  u16* dkb = dst + (size_t)z * (Kdim >> 6) * Rout * 64 + (size_t)(k0 >> 6) * Rout * 64;
  __shared__ float t1[64][65];
  __shared__ float t2[64][65];
  const int tx = threadIdx.x, ty = threadIdx.y;       // 64, 4
#pragma unroll
  for (int i = 0; i < 16; ++i) {
    const int kk = ty + 4 * i;
    t1[kk][tx] = src[(size_t)(k0 + kk) * Rdim + r0 + tx];
    if (src2) t2[kk][tx] = src2[(size_t)(k0 + kk) * Rdim + r0 + tx];
  }
  __syncthreads();
#pragma unroll
  for (int i = 0; i < 16; ++i) {
    const int rr = ty + 4 * i, r = r0 + rr;
    if (src2) {
      const int rg = 32 * (r >> 4) + (r & 15), ru = rg + 16;
      dkb[(size_t)rg * 64 + ((((tx >> 3) ^ (rg & 7)) << 3) | (tx & 7))] = f2b(t1[tx][rr]);
      dkb[(size_t)ru * 64 + ((((tx >> 3) ^ (ru & 7)) << 3) | (tx & 7))] = f2b(t2[tx][rr]);
    } else {
      dkb[(size_t)r * 64 + ((((tx >> 3) ^ (r & 7)) << 3) | (tx & 7))] = f2b(t1[tx][rr]);
    }
  }
}

// fp32 noisy top-2 router: one wave per token
__global__ void router_k(const float* __restrict__ x, const float* __restrict__ noise,
                         const float* __restrict__ Wr, const float* __restrict__ br,
                         const float* __restrict__ Wn, const float* __restrict__ bn,
                         int* __restrict__ counts, int* __restrict__ tok_e,
                         float* __restrict__ tok_g) {
  const int t = blockIdx.x;
  const int lane = threadIdx.x;
  float xv[16];
#pragma unroll
  for (int i = 0; i < 16; ++i) xv[i] = x[(size_t)t * D_ + lane + 64 * i];
  float nz[E_];
#pragma unroll
  for (int e = 0; e < E_; ++e) {
    float ar = 0.f, an = 0.f;
#pragma unroll
    for (int i = 0; i < 16; ++i) {
      int d = lane + 64 * i;
      ar += xv[i] * Wr[d * E_ + e];
      an += xv[i] * Wn[d * E_ + e];
    }
#pragma unroll
    for (int o = 32; o > 0; o >>= 1) {
      ar += __shfl_down(ar, o, 64);
      an += __shfl_down(an, o, 64);
    }
    if (lane == 0) {
      float lg = ar + br[e], nl = an + bn[e];
      float sp = (nl > 20.f) ? nl : log1pf(expf(nl));     // softplus
      nz[e] = lg + noise[(size_t)t * E_ + e] * sp;
    }
  }
  if (lane == 0) {
    int i0 = 0;
#pragma unroll
    for (int e = 1; e < E_; ++e) if (nz[e] > nz[i0]) i0 = e;
    int i1 = (i0 == 0) ? 1 : 0;
#pragma unroll
    for (int e = 0; e < E_; ++e) if (e != i0 && nz[e] > nz[i1]) i1 = e;
    float a = nz[i0], b = nz[i1];
    float m = fmaxf(a, b);
    float ea = expf(a - m), eb = expf(b - m);
    float inv = 1.f / (ea + eb);
    tok_e[2 * t] = i0; tok_e[2 * t + 1] = i1;
    tok_g[2 * t] = ea * inv; tok_g[2 * t + 1] = eb * inv;
    atomicAdd(&counts[i0], 1);
    atomicAdd(&counts[i1], 1);
  }
}

__global__ void scan_k(const int* __restrict__ counts, int* __restrict__ offsets) {
  if (threadIdx.x == 0) {
    int acc = 0;
    for (int e = 0; e < E_; ++e) { offsets[e] = acc; acc += (counts[e] + 7) & ~7; }
    offsets[E_] = acc;   // expert bases padded to 8 so the row-swizzle phase is uniform
  }
}

// gather token rows xp -> Xallp (both packed); re-swizzle chunks from t&7 to r&7
__global__ void gather_k(const u16* __restrict__ xp, const int* __restrict__ tok_e,
                         const float* __restrict__ tok_g, const int* __restrict__ offsets,
                         int* __restrict__ cursors, u16* __restrict__ Xallp,
                         int* __restrict__ row_token, float* __restrict__ row_gate) {
  const int t = blockIdx.x;
  __shared__ int rws[2];
  if (threadIdx.x < 2) {
    int e = tok_e[2 * t + threadIdx.x];
    int r = offsets[e] + atomicAdd(&cursors[e], 1);
    row_token[r] = t;
    row_gate[r] = tok_g[2 * t + threadIdx.x];
    rws[threadIdx.x] = r;
  }
  __syncthreads();
  const int r0 = rws[0], r1 = rws[1];
  const int x7 = t & 7;
#pragma unroll
  for (int it = 0; it < 2; ++it) {
    const int u = threadIdx.x + 64 * it;      // 0..127 : 16 kb x 8 chunks
    const int kb = u >> 3, cs = u & 7;
    uint4 v = *(const uint4*)(xp + ((size_t)kb * NT_ + t) * 64 + (cs << 3));
    const int c = cs ^ x7;
    *(uint4*)(Xallp + ((size_t)kb * RCAP_ + r0) * 64 + ((c ^ (r0 & 7)) << 3)) = v;
    *(uint4*)(Xallp + ((size_t)kb * RCAP_ + r1) * 64 + ((c ^ (r1 & 7)) << 3)) = v;
  }
}

// ---------- shared GEMM machinery ----------
__device__ __forceinline__ void stage_tile(const u16* ga, const u16* gb,
                                           u16* la, u16* lb, int wv, int lane) {
  // 16KB contiguous per operand tile; each glds16 copies 1KB contiguous
#pragma unroll
  for (int c = 0; c < 4; ++c) {
    glds16(ga + (wv * 4 + c) * 512 + lane * 8, la + (wv * 4 + c) * 512);
    glds16(gb + (wv * 4 + c) * 512 + lane * 8, lb + (wv * 4 + c) * 512);
  }
}

// ---------- GEMM1 (unified swiglu): C = A @ Bgu, epilogue silu(g)*u -> act packed ----------
// A packed [K/64][aRowCap][64]; B packed [E][K/64][8192][64] gu-interleaved (16-row groups)
__global__ __launch_bounds__(256, 2)
void gemm1_k(const u16* __restrict__ Ap, const u16* __restrict__ Bp, u16* __restrict__ actp,
             const int* __restrict__ neArr, const int* __restrict__ offArr,
             int fixedM, int K, int aRowCap) {
  int bx, by, e;
  if (neArr) {   // expert -> XCD pinning: lid&7 == XCD == expert
    const int lid = blockIdx.x + 32 * (blockIdx.y + (int)gridDim.y * blockIdx.z);
    e = lid & 7; const int rest = lid >> 3; bx = rest & 31; by = rest >> 5;
  } else { bx = blockIdx.x; by = blockIdx.y; e = 0; }
  const int ne = neArr ? neArr[e] : fixedM;
  const int m0 = bx * 128;
  if (m0 >= ne) return;
  const int off = offArr ? offArr[e] : 0;
  const int NKB = K >> 6;
  const size_t aKS = (size_t)aRowCap * 64;
  const size_t bKS = (size_t)8192 * 64;
  const u16* A = Ap + (size_t)(off + m0) * 64;
  const u16* B = Bp + ((size_t)e * NKB * 8192 + (size_t)by * 128) * 64;

  __shared__ __align__(16) u16 As[2][128 * 64], Bs[2][128 * 64];

  const int tid = threadIdx.x, lane = tid & 63, wv = tid >> 6;
  const int wm = (wv >> 1) * 64, wn = (wv & 1) * 64;
  const int lm = lane & 15, lq = lane >> 4;
  const int c0 = ((lq ^ (lm & 7)) << 4);   // swizzled chunk byte offset, ks=0

  f32x4 acc[4][4] = {};

  stage_tile(A, B, As[0], Bs[0], wv, lane);
  stage_tile(A + aKS, B + bKS, As[1], Bs[1], wv, lane);
  asm volatile("s_waitcnt vmcnt(8)" ::: "memory");   // tile 0 landed; tile 1 in flight
  __builtin_amdgcn_s_barrier();
  __builtin_amdgcn_sched_barrier(0);

  for (int t = 0; t < NKB; ++t) {
    const u16* as = As[t & 1];
    const u16* bs = Bs[t & 1];
#pragma unroll
    for (int ks = 0; ks < 2; ++ks) {
      const int kc = c0 ^ (ks << 6);
      bf16x8 af[4], bb[4];
#pragma unroll
      for (int i = 0; i < 4; ++i) {
        af[i] = *(const bf16x8*)((const char*)as + (wm + i * 16 + lm) * 128 + kc);
        bb[i] = *(const bf16x8*)((const char*)bs + (wn + i * 16 + lm) * 128 + kc);
      }
#pragma unroll
      for (int i = 0; i < 4; ++i)
#pragma unroll
        for (int j = 0; j < 4; ++j)
          acc[i][j] = __builtin_amdgcn_mfma_f32_16x16x32_bf16(af[i], bb[j], acc[i][j], 0, 0, 0);
    }
    if (t + 1 < NKB) {
      __builtin_amdgcn_s_barrier();                 // all waves done reading buf[t&1]
      __builtin_amdgcn_sched_barrier(0);
      if (t + 2 < NKB) {
        stage_tile(A + (size_t)(t + 2) * aKS, B + (size_t)(t + 2) * bKS,
                   As[t & 1], Bs[t & 1], wv, lane);
        asm volatile("s_waitcnt vmcnt(8)" ::: "memory");   // tile t+1 done; t+2 in flight
      } else {
        asm volatile("s_waitcnt vmcnt(0)" ::: "memory");
      }
      __builtin_amdgcn_sched_barrier(0);
      __builtin_amdgcn_s_barrier();                 // collective: tile t+1 visible to all
      __builtin_amdgcn_sched_barrier(0);
    }
  }

  // epilogue: j even = g, j odd = u (same h block); write act packed+swizzled, kb = by
  const int hbase = (wn >> 1);
#pragma unroll
  for (int i = 0; i < 4; ++i)
#pragma unroll
    for (int r = 0; r < 4; ++r) {
      const int m = m0 + wm + i * 16 + lq * 4 + r;
      if (m < ne) {
        const int row = off + m;
        u16* dr = actp + ((size_t)by * RCAP_ + row) * 64;
        const int r7 = row & 7;
#pragma unroll
        for (int jj = 0; jj < 2; ++jj) {
          float g = acc[i][2 * jj][r], u = acc[i][2 * jj + 1][r];
          float s = g / (1.f + __expf(-g)) * u;
          const int hl = hbase + jj * 16 + lm;
          dr[(((hl >> 3) ^ r7) << 3) | (hl & 7)] = f2b(s);
        }
      }
    }
}

// ---------- GEMM2: out = A @ Wd ; plain store (shared) or gated atomic scatter (routed) ----------
// A = actp packed [H/64][RCAP_][64]; B packed [E][H/64][1024][64]
__global__ __launch_bounds__(256, 2)
void gemm2_k(const u16* __restrict__ Ap, const u16* __restrict__ Bp,
             float* __restrict__ out,
             const int* __restrict__ neArr, const int* __restrict__ offArr,
             const int* __restrict__ row_token, const float* __restrict__ row_gate,
             int fixedM, int K) {
  int bx, by, e;
  if (neArr) {
    const int lid = blockIdx.x + 32 * (blockIdx.y + (int)gridDim.y * blockIdx.z);
    e = lid & 7; const int rest = lid >> 3; bx = rest & 31; by = rest >> 5;
  } else { bx = blockIdx.x; by = blockIdx.y; e = 0; }
  const int ne = neArr ? neArr[e] : fixedM;
  const int m0 = bx * 128;
  if (m0 >= ne) return;
  const int off = offArr ? offArr[e] : 0;
  const int NKB = K >> 6;
  const size_t aKS = (size_t)RCAP_ * 64;
  const size_t bKS = (size_t)1024 * 64;
  const u16* A = Ap + (size_t)(off + m0) * 64;
  const u16* B = Bp + ((size_t)e * NKB * 1024 + (size_t)by * 128) * 64;

  __shared__ __align__(16) u16 As[2][128 * 64], Bs[2][128 * 64];

  const int tid = threadIdx.x, lane = tid & 63, wv = tid >> 6;
  const int wm = (wv >> 1) * 64, wn = (wv & 1) * 64;
  const int lm = lane & 15, lq = lane >> 4;
  const int c0 = ((lq ^ (lm & 7)) << 4);

  f32x4 acc[4][4] = {};

  stage_tile(A, B, As[0], Bs[0], wv, lane);
  stage_tile(A + aKS, B + bKS, As[1], Bs[1], wv, lane);
  asm volatile("s_waitcnt vmcnt(8)" ::: "memory");
  __builtin_amdgcn_s_barrier();
  __builtin_amdgcn_sched_barrier(0);

  for (int t = 0; t < NKB; ++t) {
    const u16* as = As[t & 1];
    const u16* bs = Bs[t & 1];
#pragma unroll
    for (int ks = 0; ks < 2; ++ks) {
      const int kc = c0 ^ (ks << 6);
      bf16x8 af[4], bb[4];
#pragma unroll
      for (int i = 0; i < 4; ++i) {
        af[i] = *(const bf16x8*)((const char*)as + (wm + i * 16 + lm) * 128 + kc);
        bb[i] = *(const bf16x8*)((const char*)bs + (wn + i * 16 + lm) * 128 + kc);
      }
#pragma unroll
      for (int i = 0; i < 4; ++i)
#pragma unroll
        for (int j = 0; j < 4; ++j)
          acc[i][j] = __builtin_amdgcn_mfma_f32_16x16x32_bf16(af[i], bb[j], acc[i][j], 0, 0, 0);
    }
    if (t + 1 < NKB) {
      __builtin_amdgcn_s_barrier();
      __builtin_amdgcn_sched_barrier(0);
      if (t + 2 < NKB) {
        stage_tile(A + (size_t)(t + 2) * aKS, B + (size_t)(t + 2) * bKS,
                   As[t & 1], Bs[t & 1], wv, lane);
        asm volatile("s_waitcnt vmcnt(8)" ::: "memory");
      } else {
        asm volatile("s_waitcnt vmcnt(0)" ::: "memory");
      }
      __builtin_amdgcn_sched_barrier(0);
      __builtin_amdgcn_s_barrier();
      __builtin_amdgcn_sched_barrier(0);
    }
  }

  // C/D layout: col = lane&15, row = (lane>>4)*4 + reg  (m89-verified)
#pragma unroll
  for (int i = 0; i < 4; ++i)
#pragma unroll
    for (int r = 0; r < 4; ++r) {
      const int m = m0 + wm + i * 16 + lq * 4 + r;
      if (m < ne) {
        const int n = by * 128 + wn + lm;
        if (row_token) {
          const int t = row_token[off + m];
          const float gt = row_gate[off + m];
#pragma unroll
          for (int j = 0; j < 4; ++j)
            atomicAdd(out + (size_t)t * D_ + n + j * 16, gt * acc[i][j][r]);
        } else {
#pragma unroll
          for (int j = 0; j < 4; ++j)
            out[(size_t)m * D_ + n + j * 16] = acc[i][j][r];
        }
      }
    }
}

// ---------- host ----------
extern "C" void kernel_launch(void* const* d_in, const int* in_sizes, int n_in,
                              void* d_out, int out_size, void* d_ws, size_t ws_size,
                              hipStream_t stream) {
  const float* x     = (const float*)d_in[0];
  const float* noise = (const float*)d_in[1];
  const float* Wr    = (const float*)d_in[2];
  const float* br    = (const float*)d_in[3];
  const float* Wn    = (const float*)d_in[4];
  const float* bn    = (const float*)d_in[5];
  const float* Wg    = (const float*)d_in[6];
  const float* Wu    = (const float*)d_in[7];
  const float* Wd    = (const float*)d_in[8];
  const float* Sg    = (const float*)d_in[9];
  const float* Su    = (const float*)d_in[10];
  const float* Sd    = (const float*)d_in[11];
  float* out = (float*)d_out;

  char* base = (char*)d_ws;
  size_t off = 0;
  auto take = [&](size_t bytes) -> void* {
    void* r = base + off;
    off = (off + bytes + 255) & ~(size_t)255;
    return r;
  };
  u16* Wgup = (u16*)take((size_t)E_ * 16 * 8192 * 64 * 2);  // [E][D/64][8192 gu][64]
  u16* Wdp  = (u16*)take((size_t)E_ * 64 * 1024 * 64 * 2);  // [E][H/64][1024][64]
  u16* Sgup = (u16*)take((size_t)16 * 8192 * 64 * 2);       // [D/64][8192 gu][64]
  u16* Sdp  = (u16*)take((size_t)64 * 1024 * 64 * 2);       // [H/64][1024][64]
  u16* xp   = (u16*)take((size_t)16 * NT_ * 64 * 2);        // [D/64][NT][64]
  u16* Xallp = (u16*)take((size_t)16 * RCAP_ * 64 * 2);     // [D/64][RCAP][64]
  u16* actp  = (u16*)take((size_t)64 * RCAP_ * 64 * 2);     // [H/64][RCAP][64]
  int*   row_token = (int*)take(RCAP_ * 4);
  float* row_gate  = (float*)take(RCAP_ * 4);
  int*   tok_e = (int*)take(NT_ * 2 * 4);
  float* tok_g = (float*)take(NT_ * 2 * 4);
  int* ints = (int*)take(32 * 4);                    // counts[8] cursors[8] offsets[9]
  int* counts = ints, *cursors = ints + 8, *offsets = ints + 16;
  if (off > ws_size) return;   // ws too small: clean no-op fail

  hipLaunchKernelGGL(init_ints, dim3(1), dim3(64), 0, stream, ints, 32);
  hipLaunchKernelGGL(pack_x, dim3(NT_), dim3(256), 0, stream, x, xp);
  dim3 tb(64, 4);
  // Wg/Wu [E][D][H]: Kdim=D, Rdim=H, gu-interleaved
  hipLaunchKernelGGL(pack_b, dim3(H_ / 64, D_ / 64, E_), tb, 0, stream, Wg, Wu, Wgup, D_, H_);
  // Wd [E][H][D]: Kdim=H, Rdim=D, identity
  hipLaunchKernelGGL(pack_b, dim3(D_ / 64, H_ / 64, E_), tb, 0, stream,
                     Wd, (const float*)nullptr, Wdp, H_, D_);
  hipLaunchKernelGGL(pack_b, dim3(H_ / 64, D_ / 64, 1), tb, 0, stream, Sg, Su, Sgup, D_, H_);
  hipLaunchKernelGGL(pack_b, dim3(D_ / 64, H_ / 64, 1), tb, 0, stream,
                     Sd, (const float*)nullptr, Sdp, H_, D_);

  hipLaunchKernelGGL(router_k, dim3(NT_), dim3(64), 0, stream,
                     x, noise, Wr, br, Wn, bn, counts, tok_e, tok_g);
  hipLaunchKernelGGL(scan_k, dim3(1), dim3(64), 0, stream, counts, offsets);
  hipLaunchKernelGGL(gather_k, dim3(NT_), dim3(64), 0, stream,
                     xp, tok_e, tok_g, offsets, cursors, Xallp, row_token, row_gate);

  // shared expert: act = swiglu(x@Sg, x@Su); out = act@Sd (plain store, inits d_out)
  hipLaunchKernelGGL(gemm1_k, dim3(32, 64, 1), dim3(256), 0, stream,
                     xp, Sgup, actp, (const int*)nullptr, (const int*)nullptr, NT_, D_, NT_);
  hipLaunchKernelGGL(gemm2_k, dim3(32, 8, 1), dim3(256), 0, stream,
                     actp, Sdp, out, (const int*)nullptr, (const int*)nullptr,
                     (const int*)nullptr, (const float*)nullptr, NT_, H_);
  // routed experts: act = swiglu(Xe@Wg_e, Xe@Wu_e); out += gate * act@Wd_e
  hipLaunchKernelGGL(gemm1_k, dim3(32, 64, E_), dim3(256), 0, stream,
                     Xallp, Wgup, actp, counts, offsets, 0, D_, RCAP_);
  hipLaunchKernelGGL(gemm2_k, dim3(32, 8, E_), dim3(256), 0, stream,
                     actp, Wdp, out, counts, offsets, row_token, row_gate, 0, H_);
}

// Round 3
// 1536.540 us; speedup vs baseline: 1.0261x; 1.0261x over previous
//
#include <hip/hip_runtime.h>

typedef unsigned short u16;
typedef unsigned int u32;
typedef __attribute__((ext_vector_type(8))) __bf16 bf16x8;
typedef __attribute__((ext_vector_type(4))) float f32x4;

#define D_ 1024
#define H_ 4096
#define E_ 8
#define NT_ 4096          // B*T tokens
#define RCAP_ 8704        // 8192 rows + per-expert pad-to-8 + 256-row tile over-read slack

#define LDSH_ 8192        // u16 per half-tile (128 rows x 64)
#define LDST_ 16384       // u16 per tile buffer (256 rows x 64)

// Packed operand layout (all GEMM inputs): P[k>>6][row][64] bf16, with XOR swizzle
// baked per row: element (k&63) stored at ((((k&63)>>3) ^ (row&7))<<3) | (k&7).
// -> staging a 256-row x 64-k tile is 32KB fully contiguous (global_load_lds friendly);
// -> ds_read_b128 with the same XOR is bank-conflict-free (rule #21 pattern, verified r2: 0 conflicts).

// ---------- helpers ----------
__device__ __forceinline__ u16 f2b(float f) {   // fp32 -> bf16 bits, RNE
  u32 u = __float_as_uint(f);
  u += 0x7fffu + ((u >> 16) & 1u);
  return (u16)(u >> 16);
}

__device__ __forceinline__ void glds16(const u16* g, u16* l) {
  // async global->LDS, 16B per lane; LDS dest = wave-uniform base + lane*16
  __builtin_amdgcn_global_load_lds((const __attribute__((address_space(1))) void*)g,
                                   (__attribute__((address_space(3))) void*)l, 16, 0, 0);
}

// stage one 16KB half-tile (128 rows x 64 k): 2 x global_load_lds per wave, 8 waves
__device__ __forceinline__ void stage_half(const u16* __restrict__ g, u16* l, int wv, int lane) {
#pragma unroll
  for (int c = 0; c < 2; ++c)
    glds16(g + c * 4096 + wv * 512 + lane * 8, l + c * 4096 + wv * 512);
}

// ---------- small kernels ----------
__global__ void init_ints(int* p, int n) {
  int i = threadIdx.x;
  if (i < n) p[i] = 0;
}

// x [NT][D] f32 -> xp packed [D/64][NT][64] bf16 (swizzled by token&7)
__global__ void pack_x(const float* __restrict__ x, u16* __restrict__ xp) {
  const int t = blockIdx.x, i = threadIdx.x;          // 256 threads, 4 f32 each
  float4 v = ((const float4*)(x + (size_t)t * D_))[i];
  const int kb = i >> 4, ch = (i >> 1) & 7, sub = (i & 1) * 4;
  u16 tmp[4] = {f2b(v.x), f2b(v.y), f2b(v.z), f2b(v.w)};
  *(uint2*)(xp + ((size_t)kb * NT_ + t) * 64 + ((ch ^ (t & 7)) << 3) + sub) = *(uint2*)tmp;
}

// src [Z][Kdim][Rdim] f32 (+optional src2 for gu-interleave) -> dst [Z][Kdim/64][Rout][64] bf16
// interleave: dst rows 32q+s: s<16 -> src row 16q+s ; s>=16 -> src2 row 16q+(s-16)
// store phase: each thread owns one (row, chunk) -> one coalesced uint4 store
__global__ void pack_b(const float* __restrict__ src, const float* __restrict__ src2,
                       u16* __restrict__ dst, int Kdim, int Rdim) {
  const int r0 = blockIdx.x * 64, k0 = blockIdx.y * 64, z = blockIdx.z;
  const int Rout = src2 ? (Rdim * 2) : Rdim;
  src += (size_t)z * Kdim * Rdim;
  if (src2) src2 += (size_t)z * Kdim * Rdim;
  u16* dkb = dst + (size_t)z * (Kdim >> 6) * Rout * 64 + (size_t)(k0 >> 6) * Rout * 64;
  __shared__ float t1[64][65];
  __shared__ float t2[64][65];
  const int tx = threadIdx.x, ty = threadIdx.y;       // 64, 4
#pragma unroll
  for (int i = 0; i < 16; ++i) {
    const int kk = ty + 4 * i;
    t1[kk][tx] = src[(size_t)(k0 + kk) * Rdim + r0 + tx];
    if (src2) t2[kk][tx] = src2[(size_t)(k0 + kk) * Rdim + r0 + tx];
  }
  __syncthreads();
  const int idx = ty * 64 + tx;          // 0..255
  const int ch = idx & 7, rl0 = idx >> 3;
#pragma unroll
  for (int half = 0; half < 2; ++half) {
    const int rl = rl0 + 32 * half;      // 0..63
    const int r = r0 + rl;
    if (src2) {
      const int rg = 32 * (r >> 4) + (r & 15), ru = rg + 16;
      const int kg = (ch ^ (rg & 7)) << 3;   // rg&7 == ru&7 == r&7
      union { u16 v[8]; uint4 q; } pg, pu;
#pragma unroll
      for (int j = 0; j < 8; ++j) pg.v[j] = f2b(t1[kg + j][rl]);
#pragma unroll
      for (int j = 0; j < 8; ++j) pu.v[j] = f2b(t2[kg + j][rl]);
      *(uint4*)(dkb + (size_t)rg * 64 + ch * 8) = pg.q;
      *(uint4*)(dkb + (size_t)ru * 64 + ch * 8) = pu.q;
    } else {
      const int kc = (ch ^ (r & 7)) << 3;
      union { u16 v[8]; uint4 q; } pk;
#pragma unroll
      for (int j = 0; j < 8; ++j) pk.v[j] = f2b(t1[kc + j][rl]);
      *(uint4*)(dkb + (size_t)r * 64 + ch * 8) = pk.q;
    }
  }
}

// fp32 noisy top-2 router: one wave per token
__global__ void router_k(const float* __restrict__ x, const float* __restrict__ noise,
                         const float* __restrict__ Wr, const float* __restrict__ br,
                         const float* __restrict__ Wn, const float* __restrict__ bn,
                         int* __restrict__ counts, int* __restrict__ tok_e,
                         float* __restrict__ tok_g) {
  const int t = blockIdx.x;
  const int lane = threadIdx.x;
  float xv[16];
#pragma unroll
  for (int i = 0; i < 16; ++i) xv[i] = x[(size_t)t * D_ + lane + 64 * i];
  float nz[E_];
#pragma unroll
  for (int e = 0; e < E_; ++e) {
    float ar = 0.f, an = 0.f;
#pragma unroll
    for (int i = 0; i < 16; ++i) {
      int d = lane + 64 * i;
      ar += xv[i] * Wr[d * E_ + e];
      an += xv[i] * Wn[d * E_ + e];
    }
#pragma unroll
    for (int o = 32; o > 0; o >>= 1) {
      ar += __shfl_down(ar, o, 64);
      an += __shfl_down(an, o, 64);
    }
    if (lane == 0) {
      float lg = ar + br[e], nl = an + bn[e];
      float sp = (nl > 20.f) ? nl : log1pf(expf(nl));     // softplus
      nz[e] = lg + noise[(size_t)t * E_ + e] * sp;
    }
  }
  if (lane == 0) {
    int i0 = 0;
#pragma unroll
    for (int e = 1; e < E_; ++e) if (nz[e] > nz[i0]) i0 = e;
    int i1 = (i0 == 0) ? 1 : 0;
#pragma unroll
    for (int e = 0; e < E_; ++e) if (e != i0 && nz[e] > nz[i1]) i1 = e;
    float a = nz[i0], b = nz[i1];
    float m = fmaxf(a, b);
    float ea = expf(a - m), eb = expf(b - m);
    float inv = 1.f / (ea + eb);
    tok_e[2 * t] = i0; tok_e[2 * t + 1] = i1;
    tok_g[2 * t] = ea * inv; tok_g[2 * t + 1] = eb * inv;
    atomicAdd(&counts[i0], 1);
    atomicAdd(&counts[i1], 1);
  }
}

__global__ void scan_k(const int* __restrict__ counts, int* __restrict__ offsets) {
  if (threadIdx.x == 0) {
    int acc = 0;
    for (int e = 0; e < E_; ++e) { offsets[e] = acc; acc += (counts[e] + 7) & ~7; }
    offsets[E_] = acc;   // expert bases padded to 8 so the row-swizzle phase is uniform
  }
}

// gather token rows xp -> Xallp (both packed); re-swizzle chunks from t&7 to r&7
__global__ void gather_k(const u16* __restrict__ xp, const int* __restrict__ tok_e,
                         const float* __restrict__ tok_g, const int* __restrict__ offsets,
                         int* __restrict__ cursors, u16* __restrict__ Xallp,
                         int* __restrict__ row_token, float* __restrict__ row_gate) {
  const int t = blockIdx.x;
  __shared__ int rws[2];
  if (threadIdx.x < 2) {
    int e = tok_e[2 * t + threadIdx.x];
    int r = offsets[e] + atomicAdd(&cursors[e], 1);
    row_token[r] = t;
    row_gate[r] = tok_g[2 * t + threadIdx.x];
    rws[threadIdx.x] = r;
  }
  __syncthreads();
  const int r0 = rws[0], r1 = rws[1];
  const int x7 = t & 7;
#pragma unroll
  for (int it = 0; it < 2; ++it) {
    const int u = threadIdx.x + 64 * it;      // 0..127 : 16 kb x 8 chunks
    const int kb = u >> 3, cs = u & 7;
    uint4 v = *(const uint4*)(xp + ((size_t)kb * NT_ + t) * 64 + (cs << 3));
    const int c = cs ^ x7;
    *(uint4*)(Xallp + ((size_t)kb * RCAP_ + r0) * 64 + ((c ^ (r0 & 7)) << 3)) = v;
    *(uint4*)(Xallp + ((size_t)kb * RCAP_ + r1) * 64 + ((c ^ (r1 & 7)) << 3)) = v;
  }
}

// ---------- 256x256 8-wave phase-interleaved GEMM core (m201-style T3+T4+T5) ----------
// Per K-tile (BK=64): 4 phases. P0: read kk0 frags (12 ds_read_b128) + stage (t+1):A1.
// P1: stage (t+1):B0, MFMA hi-half kk0. P2: read kk1 (12) + stage (t+1):B1.
// P3: stage (t+2):A0 into the live buffer (A-region reads completed at P2-end barrier),
// MFMA hi kk1, then counted vmcnt(2): tile t+1 fully landed, (t+2):A0 stays in flight.
__device__ __forceinline__ void gemm_core8(
    const u16* __restrict__ A, const u16* __restrict__ B,
    size_t aKS, size_t bKS, int NKB,
    u16* As, u16* Bs, f32x4 acc[8][4], int tid) {
  const int lane = tid & 63, wv = tid >> 6;
  const int wr = wv >> 2, wc = wv & 3;
  const int lm = lane & 15, lq = lane >> 4;
  const int c0 = ((lq ^ (lm & 7)) << 4);                   // swizzled chunk byte offset, kk0
  const char* asr = (const char*)As + (wr * 128 + lm) * 128;
  const char* bsr = (const char*)Bs + (wc * 64 + lm) * 128;

  // prologue: tile0 (4 halves) + tile1:A0 ; wait tile0, keep tile1:A0 flying
  stage_half(A,         As,         wv, lane);
  stage_half(A + LDSH_, As + LDSH_, wv, lane);
  stage_half(B,         Bs,         wv, lane);
  stage_half(B + LDSH_, Bs + LDSH_, wv, lane);
  stage_half(A + aKS,   As + LDST_, wv, lane);
  asm volatile("s_waitcnt vmcnt(2)" ::: "memory");
  __builtin_amdgcn_s_barrier();
  __builtin_amdgcn_sched_barrier(0);

  for (int t = 0; t < NKB; ++t) {
    const int bo = (t & 1) << 15;            // byte offset of current buf
    const int ou = ((t & 1) ^ 1) * LDST_;    // u16 offset of other buf
    bf16x8 a[8], bb[4];
    // ---- P0 ----
#pragma unroll
    for (int i = 0; i < 8; ++i)
      a[i] = *(const bf16x8*)(asr + bo + i * 2048 + c0);
#pragma unroll
    for (int j = 0; j < 4; ++j)
      bb[j] = *(const bf16x8*)(bsr + bo + j * 2048 + c0);
    if (t + 1 < NKB) stage_half(A + (size_t)(t + 1) * aKS + LDSH_, As + ou + LDSH_, wv, lane);
    asm volatile("s_waitcnt lgkmcnt(8)" ::: "memory");
    __builtin_amdgcn_s_barrier();
    asm volatile("s_waitcnt lgkmcnt(0)" ::: "memory");
    __builtin_amdgcn_sched_barrier(0);
    __builtin_amdgcn_s_setprio(1);
#pragma unroll
    for (int i = 0; i < 4; ++i)
#pragma unroll
      for (int j = 0; j < 4; ++j)
        acc[i][j] = __builtin_amdgcn_mfma_f32_16x16x32_bf16(a[i], bb[j], acc[i][j], 0, 0, 0);
    __builtin_amdgcn_s_setprio(0);
    __builtin_amdgcn_s_barrier();
    // ---- P1 ----
    if (t + 1 < NKB) stage_half(B + (size_t)(t + 1) * bKS, Bs + ou, wv, lane);
    __builtin_amdgcn_s_barrier();
    __builtin_amdgcn_sched_barrier(0);
    __builtin_amdgcn_s_setprio(1);
#pragma unroll
    for (int i = 0; i < 4; ++i)
#pragma unroll
      for (int j = 0; j < 4; ++j)
        acc[4 + i][j] = __builtin_amdgcn_mfma_f32_16x16x32_bf16(a[4 + i], bb[j], acc[4 + i][j], 0, 0, 0);
    __builtin_amdgcn_s_setprio(0);
    __builtin_amdgcn_s_barrier();
    // ---- P2 ----
#pragma unroll
    for (int i = 0; i < 8; ++i)
      a[i] = *(const bf16x8*)(asr + bo + i * 2048 + (c0 ^ 64));
#pragma unroll
    for (int j = 0; j < 4; ++j)
      bb[j] = *(const bf16x8*)(bsr + bo + j * 2048 + (c0 ^ 64));
    if (t + 1 < NKB) stage_half(B + (size_t)(t + 1) * bKS + LDSH_, Bs + ou + LDSH_, wv, lane);
    asm volatile("s_waitcnt lgkmcnt(8)" ::: "memory");
    __builtin_amdgcn_s_barrier();
    asm volatile("s_waitcnt lgkmcnt(0)" ::: "memory");
    __builtin_amdgcn_sched_barrier(0);
    __builtin_amdgcn_s_setprio(1);
#pragma unroll
    for (int i = 0; i < 4; ++i)
#pragma unroll
      for (int j = 0; j < 4; ++j)
        acc[i][j] = __builtin_amdgcn_mfma_f32_16x16x32_bf16(a[i], bb[j], acc[i][j], 0, 0, 0);
    __builtin_amdgcn_s_setprio(0);
    __builtin_amdgcn_s_barrier();
    // ---- P3 ----
    if (t + 2 < NKB) stage_half(A + (size_t)(t + 2) * aKS, As + (bo >> 1), wv, lane);
    __builtin_amdgcn_s_barrier();
    __builtin_amdgcn_sched_barrier(0);
    __builtin_amdgcn_s_setprio(1);
#pragma unroll
    for (int i = 0; i < 4; ++i)
#pragma unroll
      for (int j = 0; j < 4; ++j)
        acc[4 + i][j] = __builtin_amdgcn_mfma_f32_16x16x32_bf16(a[4 + i], bb[j], acc[4 + i][j], 0, 0, 0);
    __builtin_amdgcn_s_setprio(0);
    if (t + 1 < NKB) {
      if (t + 2 < NKB) { asm volatile("s_waitcnt vmcnt(2)" ::: "memory"); }
      else             { asm volatile("s_waitcnt vmcnt(0)" ::: "memory"); }
      __builtin_amdgcn_sched_barrier(0);
      __builtin_amdgcn_s_barrier();
    }
  }
}

// ---------- GEMM1 (unified swiglu): C = A @ Bgu, epilogue silu(g)*u -> act packed ----------
// A packed [K/64][aRowCap][64]; B packed [E][K/64][8192][64] gu-interleaved (16-row groups)
__global__ __launch_bounds__(512, 2)
void gemm1_k(const u16* __restrict__ Ap, const u16* __restrict__ Bp, u16* __restrict__ actp,
             const int* __restrict__ neArr, const int* __restrict__ offArr,
             int fixedM, int K, int aRowCap) {
  int bx, by, e;
  if (neArr) {   // expert -> XCD pinning: lid&7 == XCD == expert (grid 16x32x8, %8==0)
    const int lid = blockIdx.x + (int)gridDim.x * (blockIdx.y + (int)gridDim.y * blockIdx.z);
    e = lid & 7; const int rest = lid >> 3; bx = rest & 15; by = rest >> 4;
  } else { bx = blockIdx.x; by = blockIdx.y; e = 0; }
  const int ne = neArr ? neArr[e] : fixedM;
  const int m0 = bx * 256;
  if (m0 >= ne) return;
  const int off = offArr ? offArr[e] : 0;
  const int n0 = by * 256;
  const int NKB = K >> 6;
  const u16* A = Ap + (size_t)(off + m0) * 64;
  const u16* B = Bp + ((size_t)e * NKB * 8192 + (size_t)n0) * 64;

  __shared__ __align__(16) u16 As[2 * LDST_], Bs[2 * LDST_];
  f32x4 acc[8][4] = {};
  const int tid = threadIdx.x;
  gemm_core8(A, B, (size_t)aRowCap * 64, (size_t)8192 * 64, NKB, As, Bs, acc, tid);

  // epilogue: j even = g, j odd = u (same h block); write act packed+swizzled
  const int lane = tid & 63, wv = tid >> 6;
  const int wr = wv >> 2, wc = wv & 3;
  const int lm = lane & 15, lq = lane >> 4;
  const int hb = (n0 + wc * 64) >> 1;
#pragma unroll
  for (int i = 0; i < 8; ++i)
#pragma unroll
    for (int r = 0; r < 4; ++r) {
      const int m = m0 + wr * 128 + i * 16 + lq * 4 + r;
      if (m < ne) {
        const int row = off + m;
        const int r7 = row & 7;
#pragma unroll
        for (int jj = 0; jj < 2; ++jj) {
          float g = acc[i][2 * jj][r], u = acc[i][2 * jj + 1][r];
          float s = g / (1.f + __expf(-g)) * u;
          const int h = hb + jj * 16 + lm;
          actp[((size_t)(h >> 6) * RCAP_ + row) * 64 + ((((h >> 3) & 7) ^ r7) << 3 | (h & 7))] = f2b(s);
        }
      }
    }
}

// ---------- GEMM2: out = A @ Wd ; plain store (shared) or gated atomic scatter (routed) ----------
// A = actp packed [H/64][RCAP_][64]; B packed [E][H/64][1024][64]
__global__ __launch_bounds__(512, 2)
void gemm2_k(const u16* __restrict__ Ap, const u16* __restrict__ Bp,
             float* __restrict__ out,
             const int* __restrict__ neArr, const int* __restrict__ offArr,
             const int* __restrict__ row_token, const float* __restrict__ row_gate,
             int fixedM, int K) {
  int bx, by, e;
  if (neArr) {   // grid 16x4x8, %8==0
    const int lid = blockIdx.x + (int)gridDim.x * (blockIdx.y + (int)gridDim.y * blockIdx.z);
    e = lid & 7; const int rest = lid >> 3; bx = rest & 15; by = rest >> 4;
  } else { bx = blockIdx.x; by = blockIdx.y; e = 0; }
  const int ne = neArr ? neArr[e] : fixedM;
  const int m0 = bx * 256;
  if (m0 >= ne) return;
  const int off = offArr ? offArr[e] : 0;
  const int n0 = by * 256;
  const int NKB = K >> 6;
  const u16* A = Ap + (size_t)(off + m0) * 64;
  const u16* B = Bp + ((size_t)e * NKB * 1024 + (size_t)n0) * 64;

  __shared__ __align__(16) u16 As[2 * LDST_], Bs[2 * LDST_];
  f32x4 acc[8][4] = {};
  const int tid = threadIdx.x;
  gemm_core8(A, B, (size_t)RCAP_ * 64, (size_t)1024 * 64, NKB, As, Bs, acc, tid);

  const int lane = tid & 63, wv = tid >> 6;
  const int wr = wv >> 2, wc = wv & 3;
  const int lm = lane & 15, lq = lane >> 4;
#pragma unroll
  for (int i = 0; i < 8; ++i)
#pragma unroll
    for (int r = 0; r < 4; ++r) {
      const int m = m0 + wr * 128 + i * 16 + lq * 4 + r;
      if (m < ne) {
        const int n = n0 + wc * 64 + lm;
        if (row_token) {
          const int tkn = row_token[off + m];
          const float gt = row_gate[off + m];
#pragma unroll
          for (int j = 0; j < 4; ++j)
            atomicAdd(out + (size_t)tkn * D_ + n + j * 16, gt * acc[i][j][r]);
        } else {
#pragma unroll
          for (int j = 0; j < 4; ++j)
            out[(size_t)m * D_ + n + j * 16] = acc[i][j][r];
        }
      }
    }
}

// ---------- host ----------
extern "C" void kernel_launch(void* const* d_in, const int* in_sizes, int n_in,
                              void* d_out, int out_size, void* d_ws, size_t ws_size,
                              hipStream_t stream) {
  const float* x     = (const float*)d_in[0];
  const float* noise = (const float*)d_in[1];
  const float* Wr    = (const float*)d_in[2];
  const float* br    = (const float*)d_in[3];
  const float* Wn    = (const float*)d_in[4];
  const float* bn    = (const float*)d_in[5];
  const float* Wg    = (const float*)d_in[6];
  const float* Wu    = (const float*)d_in[7];
  const float* Wd    = (const float*)d_in[8];
  const float* Sg    = (const float*)d_in[9];
  const float* Su    = (const float*)d_in[10];
  const float* Sd    = (const float*)d_in[11];
  float* out = (float*)d_out;

  char* base = (char*)d_ws;
  size_t off = 0;
  auto take = [&](size_t bytes) -> void* {
    void* r = base + off;
    off = (off + bytes + 255) & ~(size_t)255;
    return r;
  };
  u16* Wgup = (u16*)take((size_t)E_ * 16 * 8192 * 64 * 2);  // [E][D/64][8192 gu][64]
  u16* Wdp  = (u16*)take((size_t)E_ * 64 * 1024 * 64 * 2);  // [E][H/64][1024][64]
  u16* Sgup = (u16*)take((size_t)16 * 8192 * 64 * 2);       // [D/64][8192 gu][64]
  u16* Sdp  = (u16*)take((size_t)64 * 1024 * 64 * 2);       // [H/64][1024][64]
  u16* xp   = (u16*)take((size_t)16 * NT_ * 64 * 2);        // [D/64][NT][64]
  u16* Xallp = (u16*)take((size_t)16 * RCAP_ * 64 * 2);     // [D/64][RCAP][64]
  u16* actp  = (u16*)take((size_t)64 * RCAP_ * 64 * 2);     // [H/64][RCAP][64]
  int*   row_token = (int*)take(RCAP_ * 4);
  float* row_gate  = (float*)take(RCAP_ * 4);
  int*   tok_e = (int*)take(NT_ * 2 * 4);
  float* tok_g = (float*)take(NT_ * 2 * 4);
  int* ints = (int*)take(32 * 4);                    // counts[8] cursors[8] offsets[9]
  int* counts = ints, *cursors = ints + 8, *offsets = ints + 16;
  if (off > ws_size) return;   // ws too small: clean no-op fail

  hipLaunchKernelGGL(init_ints, dim3(1), dim3(64), 0, stream, ints, 32);
  hipLaunchKernelGGL(pack_x, dim3(NT_), dim3(256), 0, stream, x, xp);
  dim3 tb(64, 4);
  // Wg/Wu [E][D][H]: Kdim=D, Rdim=H, gu-interleaved
  hipLaunchKernelGGL(pack_b, dim3(H_ / 64, D_ / 64, E_), tb, 0, stream, Wg, Wu, Wgup, D_, H_);
  // Wd [E][H][D]: Kdim=H, Rdim=D, identity
  hipLaunchKernelGGL(pack_b, dim3(D_ / 64, H_ / 64, E_), tb, 0, stream,
                     Wd, (const float*)nullptr, Wdp, H_, D_);
  hipLaunchKernelGGL(pack_b, dim3(H_ / 64, D_ / 64, 1), tb, 0, stream, Sg, Su, Sgup, D_, H_);
  hipLaunchKernelGGL(pack_b, dim3(D_ / 64, H_ / 64, 1), tb, 0, stream,
                     Sd, (const float*)nullptr, Sdp, H_, D_);

  hipLaunchKernelGGL(router_k, dim3(NT_), dim3(64), 0, stream,
                     x, noise, Wr, br, Wn, bn, counts, tok_e, tok_g);
  hipLaunchKernelGGL(scan_k, dim3(1), dim3(64), 0, stream, counts, offsets);
  hipLaunchKernelGGL(gather_k, dim3(NT_), dim3(64), 0, stream,
                     xp, tok_e, tok_g, offsets, cursors, Xallp, row_token, row_gate);

  // shared expert: act = swiglu(x@Sg, x@Su); out = act@Sd (plain store, inits d_out)
  hipLaunchKernelGGL(gemm1_k, dim3(16, 32, 1), dim3(512), 0, stream,
                     xp, Sgup, actp, (const int*)nullptr, (const int*)nullptr, NT_, D_, NT_);
  hipLaunchKernelGGL(gemm2_k, dim3(16, 4, 1), dim3(512), 0, stream,
                     actp, Sdp, out, (const int*)nullptr, (const int*)nullptr,
                     (const int*)nullptr, (const float*)nullptr, NT_, H_);
  // routed experts: act = swiglu(Xe@Wg_e, Xe@Wu_e); out += gate * act@Wd_e
  hipLaunchKernelGGL(gemm1_k, dim3(16, 32, E_), dim3(512), 0, stream,
                     Xallp, Wgup, actp, counts, offsets, 0, D_, RCAP_);
  hipLaunchKernelGGL(gemm2_k, dim3(16, 4, E_), dim3(512), 0, stream,
                     actp, Wdp, out, counts, offsets, row_token, row_gate, 0, H_);
}